// Round 12
// baseline (1319.546 us; speedup 1.0000x reference)
//
#include <hip/hip_runtime.h>

#define DIM 256
#define G 1280           // persistent grid: 5 blocks/CU x 256 CUs (enforced resident)
#define NSUB 16
#define SUBSZ (G / NSUB) // 80

typedef __attribute__((ext_vector_type(8))) short short8;
typedef __attribute__((ext_vector_type(8))) unsigned short u16x8;
typedef __attribute__((ext_vector_type(4))) float f32x4;

__device__ __forceinline__ unsigned short f32_to_bf16(float x) {
    unsigned int u = __float_as_uint(x);
    unsigned int r = u + 0x7FFFu + ((u >> 16) & 1u);
    return (unsigned short)(r >> 16);
}
__device__ __forceinline__ float bf16_to_f32(unsigned short h) {
    return __uint_as_float(((unsigned int)h) << 16);
}

__device__ __forceinline__ void load_lds16(const void* g, void* l) {
    __builtin_amdgcn_global_load_lds(
        (const __attribute__((address_space(1))) unsigned int*)g,
        (__attribute__((address_space(3))) unsigned int*)l, 16, 0, 0);
}

// two-level grid barrier: NSUB sub-counters (128B apart) -> 1 master counter.
// monotonic counts (no reset); bar zeroed by hipMemsetAsync each launch.
__device__ __forceinline__ void gsync(int* bar, int round) {
    __syncthreads();
    if (threadIdx.x == 0) {
        __threadfence();   // release this block's writes (agent scope, L2 wb)
        int sub = blockIdx.x & (NSUB - 1);
        int prev = atomicAdd(&bar[sub * 32], 1);
        if (prev == round * SUBSZ + (SUBSZ - 1))
            atomicAdd(&bar[NSUB * 32], 1);
        while (__hip_atomic_load(&bar[NSUB * 32], __ATOMIC_RELAXED,
                                 __HIP_MEMORY_SCOPE_AGENT) < (round + 1) * NSUB)
            __builtin_amdgcn_s_sleep(1);
        __threadfence();   // acquire: invalidate stale cached lines
    }
    __syncthreads();
}

__global__ __launch_bounds__(256, 5) void mega_kernel(
    const float* x0, const int* eidx, const float* W,
    int N, int E, int nb, int ntiles, int ngroups, int n4,
    int* deg, int* row_start, int* excl, int* bsums, float* inv_deg,
    int* csr_src, unsigned short* Wt, unsigned short* x0b,
    unsigned short* h, unsigned short* act_a, unsigned short* act_b,
    float* out, int* bar)
{
    const int* srcp = eidx;
    const int* dstp = eidx + E;
    int* cursor = deg + N;

    __shared__ unsigned short As[128 * 32];  // 8 KB (also scan scratch)
    __shared__ unsigned short Bs[128 * 32];  // 8 KB

    const int tid = threadIdx.x;
    const int bid = blockIdx.x;
    const int gthread = bid * 256 + tid;
    const int GT = G * 256;
    int round = 0;

    // ---- P0: zero deg + cursor (adjacent 2N ints) ----
    for (int i = gthread; i < 2 * N; i += GT) deg[i] = 0;
    gsync(bar, round++);

    // ---- P1: degree histogram ----
    for (int e = gthread; e < E; e += GT) atomicAdd(&deg[dstp[e]], 1);
    gsync(bar, round++);

    // ---- P2: scan1 (per-block exclusive scan + block sums) ----
    {
        int* s = (int*)As;
        if (bid < nb) {
            int i = bid * 256 + tid;
            int v = (i < N) ? deg[i] : 0;
            s[tid] = v;
            __syncthreads();
            for (int off = 1; off < 256; off <<= 1) {
                int t2 = (tid >= off) ? s[tid - off] : 0;
                __syncthreads();
                s[tid] += t2;
                __syncthreads();
            }
            if (i <= N) excl[i] = s[tid] - v;
            if (tid == 255) bsums[bid] = s[tid];
        }
    }
    gsync(bar, round++);

    // ---- P3: scan2 (block 0 scans block sums) ----
    {
        int* s = (int*)As;
        if (bid == 0) {
            int v = (tid < nb) ? bsums[tid] : 0;
            s[tid] = v;
            __syncthreads();
            for (int off = 1; off < 256; off <<= 1) {
                int t2 = (tid >= off) ? s[tid - off] : 0;
                __syncthreads();
                s[tid] += t2;
                __syncthreads();
            }
            if (tid < nb) bsums[tid] = s[tid] - v;
        }
    }
    gsync(bar, round++);

    // ---- P4: scan3 (row_start) + inv_deg ----
    if (bid < nb) {
        int i = bid * 256 + tid;
        if (i <= N) row_start[i] = excl[i] + bsums[bid];
        if (i < N) inv_deg[i] = 1.0f / (float)max(deg[i], 1);
    }
    gsync(bar, round++);

    // ---- P5: CSR fill + Wt transpose + x0 -> bf16 ----
    for (int e = gthread; e < E; e += GT) {
        int d = dstp[e];
        int pos = row_start[d] + atomicAdd(&cursor[d], 1);
        csr_src[pos] = srcp[e];
    }
    if (bid < DIM) Wt[tid * DIM + bid] = f32_to_bf16(W[bid * DIM + tid]);
    for (int i = gthread; i < n4; i += GT) {
        float4 v = ((const float4*)x0)[i];
        ushort4 o;
        o.x = f32_to_bf16(v.x); o.y = f32_to_bf16(v.y);
        o.z = f32_to_bf16(v.z); o.w = f32_to_bf16(v.w);
        ((ushort4*)x0b)[i] = o;
    }
    gsync(bar, round++);

    // ---- layers ----
    const int w    = tid >> 6;
    const int lane = tid & 63;
    const int half = lane >> 5;
    const int c    = (lane & 31) * 8;
    const int lm   = lane & 15;
    const int q    = lane >> 4;
    const int sr   = tid >> 2;
    const int sg   = (tid & 3) * 8;

    const unsigned short* gsrc = x0b;
    for (int L = 0; L < 5; L++) {
        // -- agg phase: grid-stride over 4-node groups, 1 node per wave (R10-verified) --
        for (int vg = bid; vg < ngroups; vg += G) {
            int node = vg * 4 + w;
            if (node < N) {             // wave-uniform
                int beg = row_start[node];
                int end = row_start[node + 1];
                float a[8];
                #pragma unroll
                for (int j = 0; j < 8; j++) a[j] = 0.f;
                int e = beg;
                for (; e + 4 <= end; e += 4) {
                    int s0 = csr_src[e + half];
                    int s1 = csr_src[e + 2 + half];
                    u16x8 v0 = *(const u16x8*)(gsrc + (size_t)s0 * DIM + c);
                    u16x8 v1 = *(const u16x8*)(gsrc + (size_t)s1 * DIM + c);
                    #pragma unroll
                    for (int j = 0; j < 8; j++) a[j] += bf16_to_f32(v0[j]) + bf16_to_f32(v1[j]);
                }
                if (e + 2 <= end) {
                    int s0 = csr_src[e + half];
                    u16x8 v0 = *(const u16x8*)(gsrc + (size_t)s0 * DIM + c);
                    #pragma unroll
                    for (int j = 0; j < 8; j++) a[j] += bf16_to_f32(v0[j]);
                    e += 2;
                }
                if (e < end && half == 0) {
                    int s0 = csr_src[e];
                    u16x8 v0 = *(const u16x8*)(gsrc + (size_t)s0 * DIM + c);
                    #pragma unroll
                    for (int j = 0; j < 8; j++) a[j] += bf16_to_f32(v0[j]);
                }
                #pragma unroll
                for (int j = 0; j < 8; j++) a[j] += __shfl_xor(a[j], 32);
                if (half == 0) {
                    float scale = 0.9f * inv_deg[node];
                    u16x8 xv = *(const u16x8*)(x0b + (size_t)node * DIM + c);
                    u16x8 o;
                    #pragma unroll
                    for (int j = 0; j < 8; j++)
                        o[j] = f32_to_bf16(0.1f * bf16_to_f32(xv[j]) + scale * a[j]);
                    *(u16x8*)(h + (size_t)node * DIM + c) = o;
                }
            }
        }
        gsync(bar, round++);

        // -- gemm phase: grid-stride over 128x128 tiles (R10-verified body) --
        unsigned short* actout = (L & 1) ? act_b : act_a;
        const bool lastL = (L == 4);
        for (int vt = bid; vt < ntiles; vt += G) {
            const int m0 = (vt >> 1) * 128;
            const int n0 = (vt & 1) * 128;
            const int wm = w >> 1, wn = w & 1;

            f32x4 acc[4][4];
            #pragma unroll
            for (int mi = 0; mi < 4; mi++)
                #pragma unroll
                for (int ni = 0; ni < 4; ni++)
                    acc[mi][ni] = (f32x4){0.f, 0.f, 0.f, 0.f};

            for (int kb = 0; kb < DIM; kb += 32) {
                __syncthreads();
                #pragma unroll
                for (int hf = 0; hf < 2; hf++) {
                    int r = hf * 64 + sr;
                    int ldso = (hf * 256 + tid) * 8;
                    load_lds16(h  + (size_t)(m0 + r) * DIM + kb + sg, &As[ldso]);
                    load_lds16(Wt + (size_t)(n0 + r) * DIM + kb + sg, &Bs[ldso]);
                }
                __syncthreads();

                short8 a[4];
                #pragma unroll
                for (int mi = 0; mi < 4; mi++) {
                    int row = wm * 64 + mi * 16 + lm;
                    a[mi] = *(const short8*)&As[row * 32 + q * 8];
                }
                #pragma unroll
                for (int ni = 0; ni < 4; ni++) {
                    int row = wn * 64 + ni * 16 + lm;
                    short8 b = *(const short8*)&Bs[row * 32 + q * 8];
                    #pragma unroll
                    for (int mi = 0; mi < 4; mi++)
                        acc[mi][ni] = __builtin_amdgcn_mfma_f32_16x16x32_bf16(a[mi], b, acc[mi][ni], 0, 0, 0);
                }
            }

            #pragma unroll
            for (int mi = 0; mi < 4; mi++) {
                const int rowb = m0 + wm * 64 + mi * 16 + q * 4;
                #pragma unroll
                for (int ni = 0; ni < 4; ni++) {
                    const int col = n0 + wn * 64 + ni * 16 + lm;
                    #pragma unroll
                    for (int r4 = 0; r4 < 4; r4++) {
                        int row = rowb + r4;
                        if (row < N) {
                            float v = fmaxf(acc[mi][ni][r4], 0.0f);
                            if (lastL) out[(size_t)row * DIM + col] = v;
                            else       actout[(size_t)row * DIM + col] = f32_to_bf16(v);
                        }
                    }
                }
            }
        }
        if (L < 4) gsync(bar, round++);
        gsrc = actout;
    }
}

extern "C" void kernel_launch(void* const* d_in, const int* in_sizes, int n_in,
                              void* d_out, int out_size, void* d_ws, size_t ws_size,
                              hipStream_t stream) {
    const float* x0  = (const float*)d_in[0];
    const int*   ei  = (const int*)d_in[1];
    const float* W   = (const float*)d_in[2];
    float*       out = (float*)d_out;

    const int N = in_sizes[0] / DIM;
    const int E = in_sizes[1] / 2;
    const int N_pad = (N + 127) & ~127;

    const int nb      = (N + 1 + 255) / 256;     // scan blocks (<=256 required)
    const int ntiles  = (N_pad / 128) * 2;       // gemm tiles
    const int ngroups = (N + 3) / 4;             // agg 4-node groups
    const int n4      = N * DIM / 4;

    char* ws = (char*)d_ws;
    size_t off = 0;
    auto alloc = [&](size_t bytes) { char* p = ws + off; off += (bytes + 255) & ~size_t(255); return p; };
    unsigned short* h       = (unsigned short*)alloc((size_t)N_pad * DIM * 2);
    unsigned short* act_a   = (unsigned short*)alloc((size_t)N_pad * DIM * 2);
    unsigned short* act_b   = (unsigned short*)alloc((size_t)N_pad * DIM * 2);
    unsigned short* x0b     = (unsigned short*)alloc((size_t)N_pad * DIM * 2);
    unsigned short* Wt      = (unsigned short*)alloc((size_t)DIM * DIM * 2);
    float* inv_deg  = (float*)alloc((size_t)N * 4);
    int*   deg      = (int*)  alloc((size_t)N * 4 * 2);   // deg + cursor adjacent
    int*   row_start= (int*)  alloc((size_t)(N + 1) * 4);
    int*   excl     = (int*)  alloc((size_t)(N + 1) * 4);
    int*   bsums    = (int*)  alloc((size_t)nb * 4);
    int*   csr_src  = (int*)  alloc((size_t)E * 4);
    int*   bar      = (int*)  alloc((size_t)(NSUB * 32 + 32) * 4);

    hipMemsetAsync(bar, 0, (size_t)(NSUB * 32 + 32) * 4, stream);
    mega_kernel<<<G, 256, 0, stream>>>(x0, ei, W, N, E, nb, ntiles, ngroups, n4,
                                       deg, row_start, excl, bsums, inv_deg,
                                       csr_src, Wt, x0b, h, act_a, act_b, out, bar);
}

// Round 13
// 519.760 us; speedup vs baseline: 2.5388x; 2.5388x over previous
//
#include <hip/hip_runtime.h>

#define DIM 256
#define SCAN_T 1024

typedef __attribute__((ext_vector_type(8))) short short8;
typedef __attribute__((ext_vector_type(8))) unsigned short u16x8;
typedef __attribute__((ext_vector_type(4))) float f32x4;

__device__ __forceinline__ unsigned short f32_to_bf16(float x) {
    unsigned int u = __float_as_uint(x);
    unsigned int r = u + 0x7FFFu + ((u >> 16) & 1u);
    return (unsigned short)(r >> 16);
}
__device__ __forceinline__ float bf16_to_f32(unsigned short h) {
    return __uint_as_float(((unsigned int)h) << 16);
}

__device__ __forceinline__ void load_lds16(const void* g, void* l) {
    __builtin_amdgcn_global_load_lds(
        (const __attribute__((address_space(1))) unsigned int*)g,
        (__attribute__((address_space(3))) unsigned int*)l, 16, 0, 0);
}

// ---------------- merged: degree histogram + Wt transpose + x0 cast ----------------
// blocks [0,nd): deg; [nd, nd+DIM): Wt; [nd+DIM, ...): x0 -> bf16
__global__ void degprep_kernel(const int* __restrict__ dst, int E, int* __restrict__ deg,
                               const float* __restrict__ W, unsigned short* __restrict__ Wt,
                               const float* __restrict__ x0, unsigned short* __restrict__ x0b,
                               int n4, int nd) {
    const int b = blockIdx.x;
    const int tid = threadIdx.x;
    if (b < nd) {
        int e = b * 256 + tid;
        if (e < E) atomicAdd(&deg[dst[e]], 1);
    } else if (b < nd + DIM) {
        int k = b - nd;
        Wt[tid * DIM + k] = f32_to_bf16(W[k * DIM + tid]);
    } else {
        int i = (b - nd - DIM) * 256 + tid;
        if (i < n4) {
            float4 v = ((const float4*)x0)[i];
            ushort4 o;
            o.x = f32_to_bf16(v.x); o.y = f32_to_bf16(v.y);
            o.z = f32_to_bf16(v.z); o.w = f32_to_bf16(v.w);
            ((ushort4*)x0b)[i] = o;
        }
    }
}

// ---------------- single-block scan: deg -> row_start, cursor(=row_start), inv_deg ----
__global__ __launch_bounds__(SCAN_T) void scan_kernel(
    const int* __restrict__ deg, int N,
    int* __restrict__ row_start, int* __restrict__ cursor, float* __restrict__ inv_deg)
{
    __shared__ int tsum[SCAN_T];
    const int tid = threadIdx.x;
    const int ch = (N + SCAN_T) / SCAN_T;   // per-thread chunk; covers N+1 elements
    const int base = tid * ch;

    int s = 0;
    for (int i = 0; i < ch; i++) {
        int idx = base + i;
        if (idx < N) s += deg[idx];
    }
    tsum[tid] = s;
    __syncthreads();
    for (int off = 1; off < SCAN_T; off <<= 1) {
        int v = (tid >= off) ? tsum[tid - off] : 0;
        __syncthreads();
        tsum[tid] += v;
        __syncthreads();
    }
    int run = (tid > 0) ? tsum[tid - 1] : 0;   // exclusive prefix for this chunk
    for (int i = 0; i < ch; i++) {
        int idx = base + i;
        if (idx <= N) {
            row_start[idx] = run;
            if (idx < N) {
                int d = deg[idx];
                cursor[idx] = run;
                inv_deg[idx] = 1.0f / (float)max(d, 1);
                run += d;
            }
        }
    }
}

// ---------------- CSR bucket fill (cursor pre-seeded with row_start) ----------------
__global__ void fill_kernel(const int* __restrict__ src, const int* __restrict__ dst, int E,
                            int* __restrict__ cursor, int* __restrict__ csr_src) {
    int e = blockIdx.x * blockDim.x + threadIdx.x;
    if (e < E) {
        int pos = atomicAdd(&cursor[dst[e]], 1);
        csr_src[pos] = src[e];
    }
}

// ---------------- gather aggregation (bf16 src, 16B/lane) + residual mix -> bf16 h ----
// one 64-lane wave per node; lane owns 8 cols; wave halves process 2 edges concurrently.
// (R10-verified)
__global__ __launch_bounds__(256) void aggregate_kernel(
    const unsigned short* __restrict__ xh, const unsigned short* __restrict__ x0b,
    const int* __restrict__ row_start, const int* __restrict__ csr_src,
    const float* __restrict__ inv_deg,
    unsigned short* __restrict__ h, int N)
{
    int node = blockIdx.x * 4 + (threadIdx.x >> 6);
    if (node >= N) return;
    const int lane = threadIdx.x & 63;
    const int half = lane >> 5;
    const int c    = (lane & 31) * 8;

    int beg = row_start[node];
    int end = row_start[node + 1];

    float a[8];
    #pragma unroll
    for (int j = 0; j < 8; j++) a[j] = 0.f;

    int e = beg;
    for (; e + 4 <= end; e += 4) {
        int s0 = csr_src[e + half];
        int s1 = csr_src[e + 2 + half];
        u16x8 v0 = *(const u16x8*)(xh + (size_t)s0 * DIM + c);
        u16x8 v1 = *(const u16x8*)(xh + (size_t)s1 * DIM + c);
        #pragma unroll
        for (int j = 0; j < 8; j++) a[j] += bf16_to_f32(v0[j]) + bf16_to_f32(v1[j]);
    }
    if (e + 2 <= end) {
        int s0 = csr_src[e + half];
        u16x8 v0 = *(const u16x8*)(xh + (size_t)s0 * DIM + c);
        #pragma unroll
        for (int j = 0; j < 8; j++) a[j] += bf16_to_f32(v0[j]);
        e += 2;
    }
    if (e < end && half == 0) {
        int s0 = csr_src[e];
        u16x8 v0 = *(const u16x8*)(xh + (size_t)s0 * DIM + c);
        #pragma unroll
        for (int j = 0; j < 8; j++) a[j] += bf16_to_f32(v0[j]);
    }

    #pragma unroll
    for (int j = 0; j < 8; j++) a[j] += __shfl_xor(a[j], 32);

    if (half == 0) {
        float scale = 0.9f * inv_deg[node];
        u16x8 xv = *(const u16x8*)(x0b + (size_t)node * DIM + c);
        u16x8 o;
        #pragma unroll
        for (int j = 0; j < 8; j++)
            o[j] = f32_to_bf16(0.1f * bf16_to_f32(xv[j]) + scale * a[j]);
        *(u16x8*)(h + (size_t)node * DIM + c) = o;
    }
}

// ---------------- full-width LDS-staged MFMA GEMM: out = relu(h @ W) ----------------
// 64 rows x 256 cols per 256-thread block; wave w owns cols w*64..+64, 4x4 frags.
// h fetched once per layer (no grid.y split). MFMA order per output identical to R10.
template <bool LAST>
__global__ __launch_bounds__(256) void gemm_kernel(
    const unsigned short* __restrict__ h, const unsigned short* __restrict__ Wt,
    float* __restrict__ out_f32, unsigned short* __restrict__ out_bf16, int N)
{
    __shared__ unsigned short As[64 * 32];    // 4 KB
    __shared__ unsigned short Bs[256 * 32];   // 16 KB

    const int t    = threadIdx.x;
    const int w    = t >> 6;
    const int lane = t & 63;
    const int lm   = lane & 15;
    const int q    = lane >> 4;
    const int m0   = blockIdx.x * 64;
    const int sr   = t >> 2;       // 0..63
    const int sg   = (t & 3) * 8;  // 16B granule

    f32x4 acc[4][4];
    #pragma unroll
    for (int mi = 0; mi < 4; mi++)
        #pragma unroll
        for (int ni = 0; ni < 4; ni++)
            acc[mi][ni] = (f32x4){0.f, 0.f, 0.f, 0.f};

    for (int kb = 0; kb < DIM; kb += 32) {
        __syncthreads();
        load_lds16(h + (size_t)(m0 + sr) * DIM + kb + sg, &As[t * 8]);
        #pragma unroll
        for (int hf = 0; hf < 4; hf++)
            load_lds16(Wt + (size_t)(hf * 64 + sr) * DIM + kb + sg, &Bs[hf * 2048 + t * 8]);
        __syncthreads();

        short8 a[4];
        #pragma unroll
        for (int mi = 0; mi < 4; mi++)
            a[mi] = *(const short8*)&As[(mi * 16 + lm) * 32 + q * 8];
        #pragma unroll
        for (int ni = 0; ni < 4; ni++) {
            short8 b = *(const short8*)&Bs[(w * 64 + ni * 16 + lm) * 32 + q * 8];
            #pragma unroll
            for (int mi = 0; mi < 4; mi++)
                acc[mi][ni] = __builtin_amdgcn_mfma_f32_16x16x32_bf16(a[mi], b, acc[mi][ni], 0, 0, 0);
        }
    }

    // epilogue: C/D layout col=lane&15, row=q*4+reg (R4-verified)
    #pragma unroll
    for (int mi = 0; mi < 4; mi++) {
        const int rowb = m0 + mi * 16 + q * 4;
        #pragma unroll
        for (int ni = 0; ni < 4; ni++) {
            const int col = w * 64 + ni * 16 + lm;
            #pragma unroll
            for (int r = 0; r < 4; r++) {
                int row = rowb + r;
                if (row < N) {
                    float v = fmaxf(acc[mi][ni][r], 0.0f);
                    if (LAST) out_f32[(size_t)row * DIM + col] = v;
                    else      out_bf16[(size_t)row * DIM + col] = f32_to_bf16(v);
                }
            }
        }
    }
}

extern "C" void kernel_launch(void* const* d_in, const int* in_sizes, int n_in,
                              void* d_out, int out_size, void* d_ws, size_t ws_size,
                              hipStream_t stream) {
    const float* x0  = (const float*)d_in[0];
    const int*   ei  = (const int*)d_in[1];
    const float* W   = (const float*)d_in[2];
    float*       out = (float*)d_out;

    const int N = in_sizes[0] / DIM;
    const int E = in_sizes[1] / 2;
    const int N_pad = (N + 127) & ~127;
    const int* src = ei;
    const int* dst = ei + E;

    const int nd = (E + 255) / 256;
    const int n4 = N * DIM / 4;
    const int np = (n4 + 255) / 256;

    char* ws = (char*)d_ws;
    size_t off = 0;
    auto alloc = [&](size_t bytes) { char* p = ws + off; off += (bytes + 15) & ~size_t(15); return p; };
    unsigned short* h       = (unsigned short*)alloc((size_t)N_pad * DIM * 2);
    unsigned short* act     = (unsigned short*)alloc((size_t)N_pad * DIM * 2);
    unsigned short* x0b     = (unsigned short*)alloc((size_t)N_pad * DIM * 2);
    unsigned short* Wt      = (unsigned short*)alloc((size_t)DIM * DIM * 2);
    float* inv_deg  = (float*)alloc((size_t)N * 4);
    int*   deg      = (int*)  alloc((size_t)N * 4);
    int*   cursor   = (int*)  alloc((size_t)N * 4);
    int*   row_start= (int*)  alloc((size_t)(N + 1) * 4);
    int*   csr_src  = (int*)  alloc((size_t)E * 4);

    // ---- CSR build + prep: 4 dispatches ----
    hipMemsetAsync(deg, 0, (size_t)N * 4, stream);
    degprep_kernel<<<nd + DIM + np, 256, 0, stream>>>(dst, E, deg, W, Wt, x0, x0b, n4, nd);
    scan_kernel<<<1, SCAN_T, 0, stream>>>(deg, N, row_start, cursor, inv_deg);
    fill_kernel<<<nd, 256, 0, stream>>>(src, dst, E, cursor, csr_src);

    // ---- 5 GCN layers (layer 0 gathers from x0b; then act) ----
    const int ggrid = N_pad / 64;
    for (int layer = 0; layer < 5; layer++) {
        const unsigned short* gsrc = (layer == 0) ? x0b : act;
        aggregate_kernel<<<(N + 3) / 4, 256, 0, stream>>>(gsrc, x0b, row_start, csr_src,
                                                          inv_deg, h, N);
        if (layer == 4)
            gemm_kernel<true><<<ggrid, 256, 0, stream>>>(h, Wt, out, nullptr, N);
        else
            gemm_kernel<false><<<ggrid, 256, 0, stream>>>(h, Wt, nullptr, act, N);
    }
}